// Round 1
// baseline (3348.055 us; speedup 1.0000x reference)
//
#include <hip/hip_runtime.h>
#include <stdint.h>

#define S_LEN 2048
#define B_SZ  64
#define I_SZ  512
#define H_SZ  512

typedef __attribute__((ext_vector_type(8))) short bf16x8;
typedef __attribute__((ext_vector_type(4))) float f32x4;

// f32 -> bf16 (RNE), no header dependency
__device__ __forceinline__ uint16_t f2b(float x) {
    uint32_t u = __float_as_uint(x);
    uint32_t r = (u + 0x7fffu + ((u >> 16) & 1u)) >> 16;
    return (uint16_t)r;
}

// ---------------- kernel 1: convert weights to bf16 in ws ----------------
__global__ void cvt_weights_kernel(const float* __restrict__ wih,
                                   const float* __restrict__ whh,
                                   uint16_t* __restrict__ wihb,
                                   uint16_t* __restrict__ whhb) {
    int i = (blockIdx.x * blockDim.x + threadIdx.x) * 4;   // 256 blk * 256 thr * 4 = 262144
    float4 a = *reinterpret_cast<const float4*>(wih + i);
    float4 b = *reinterpret_cast<const float4*>(whh + i);
    union { uint16_t u[4]; uint2 v; } pa, pb;
    pa.u[0] = f2b(a.x); pa.u[1] = f2b(a.y); pa.u[2] = f2b(a.z); pa.u[3] = f2b(a.w);
    pb.u[0] = f2b(b.x); pb.u[1] = f2b(b.y); pb.u[2] = f2b(b.z); pb.u[3] = f2b(b.w);
    *reinterpret_cast<uint2*>(wihb + i) = pa.v;
    *reinterpret_cast<uint2*>(whhb + i) = pb.v;
}

// ---------------- kernel 2: x_proj GEMM  xp[sb,h] = input[sb,:] . Wih[h,:] + bias ---
#define BM 128
#define BN 128
#define BK 32

__launch_bounds__(256)
__global__ void xproj_gemm_kernel(const float* __restrict__ inp,      // [SB, I] f32
                                  const uint16_t* __restrict__ wihb,  // [H, I] bf16
                                  const float* __restrict__ bih,
                                  const float* __restrict__ bhh,
                                  float* __restrict__ xp)             // [SB, H] f32 (= d_out)
{
    __shared__ __align__(16) uint16_t Asm[2][BM * BK];
    __shared__ __align__(16) uint16_t Bsm[2][BN * BK];

    const int tid  = threadIdx.x;
    const int lane = tid & 63;
    const int w    = tid >> 6;            // 0..3
    const int wm   = (w >> 1) * 64;
    const int wn   = (w & 1) * 64;
    const int bid  = blockIdx.x;
    const int m0   = (bid >> 2) * BM;     // 1024 m-tiles
    const int n0   = (bid & 3) * BN;      // 4 n-tiles

    const int srow  = tid >> 1;           // 0..127
    const int shalf = (tid & 1) * 16;     // k offset 0/16

    float bsum[4];
#pragma unroll
    for (int nn = 0; nn < 4; ++nn) {
        int col = n0 + wn + nn * 16 + (lane & 15);
        bsum[nn] = bih[col] + bhh[col];
    }

    f32x4 acc[4][4];
#pragma unroll
    for (int mm = 0; mm < 4; ++mm)
#pragma unroll
        for (int nn = 0; nn < 4; ++nn)
            acc[mm][nn] = f32x4{0.f, 0.f, 0.f, 0.f};

    float4 ar[4];
    bf16x8 br[2];

    auto loadA = [&](int kt) {
        const float* g = inp + (size_t)(m0 + srow) * I_SZ + kt * BK + shalf;
#pragma unroll
        for (int q = 0; q < 4; ++q) ar[q] = *reinterpret_cast<const float4*>(g + q * 4);
    };
    auto loadB = [&](int kt) {
        const uint16_t* g = wihb + (size_t)(n0 + srow) * I_SZ + kt * BK + shalf;
        br[0] = *reinterpret_cast<const bf16x8*>(g);
        br[1] = *reinterpret_cast<const bf16x8*>(g + 8);
    };
    auto writeA = [&](int buf) {
        alignas(16) uint16_t tmp[16];
#pragma unroll
        for (int q = 0; q < 4; ++q) {
            tmp[q * 4 + 0] = f2b(ar[q].x); tmp[q * 4 + 1] = f2b(ar[q].y);
            tmp[q * 4 + 2] = f2b(ar[q].z); tmp[q * 4 + 3] = f2b(ar[q].w);
        }
        *reinterpret_cast<bf16x8*>(&Asm[buf][srow * BK + shalf])     = *reinterpret_cast<bf16x8*>(tmp);
        *reinterpret_cast<bf16x8*>(&Asm[buf][srow * BK + shalf + 8]) = *reinterpret_cast<bf16x8*>(tmp + 8);
    };
    auto writeB = [&](int buf) {
        *reinterpret_cast<bf16x8*>(&Bsm[buf][srow * BK + shalf])     = br[0];
        *reinterpret_cast<bf16x8*>(&Bsm[buf][srow * BK + shalf + 8]) = br[1];
    };

    loadA(0); loadB(0); writeA(0); writeB(0);
    __syncthreads();

    for (int kt = 0; kt < I_SZ / BK; ++kt) {
        const int cur = kt & 1;
        const bool more = (kt + 1) < I_SZ / BK;
        if (more) { loadA(kt + 1); loadB(kt + 1); }

        bf16x8 afrag[4], bfrag[4];
#pragma unroll
        for (int mm = 0; mm < 4; ++mm)
            afrag[mm] = *reinterpret_cast<const bf16x8*>(
                &Asm[cur][(wm + mm * 16 + (lane & 15)) * BK + (lane >> 4) * 8]);
#pragma unroll
        for (int nn = 0; nn < 4; ++nn)
            bfrag[nn] = *reinterpret_cast<const bf16x8*>(
                &Bsm[cur][(wn + nn * 16 + (lane & 15)) * BK + (lane >> 4) * 8]);
#pragma unroll
        for (int mm = 0; mm < 4; ++mm)
#pragma unroll
            for (int nn = 0; nn < 4; ++nn)
                acc[mm][nn] = __builtin_amdgcn_mfma_f32_16x16x32_bf16(
                    afrag[mm], bfrag[nn], acc[mm][nn], 0, 0, 0);

        if (more) { writeA(cur ^ 1); writeB(cur ^ 1); }
        __syncthreads();
    }

#pragma unroll
    for (int mm = 0; mm < 4; ++mm) {
        const int rbase = m0 + wm + mm * 16 + (lane >> 4) * 4;
#pragma unroll
        for (int nn = 0; nn < 4; ++nn) {
            const int col = n0 + wn + nn * 16 + (lane & 15);
#pragma unroll
            for (int r = 0; r < 4; ++r)
                xp[(size_t)(rbase + r) * H_SZ + col] = acc[mm][nn][r] + bsum[nn];
        }
    }
}

// ---------------- kernel 3: recurrence. One block per batch element. --------------
// h_new[j] = tanh(xp[s,b,j] + sum_k Whh[j,k] h[k]); xp lives in d_out, overwritten.
__launch_bounds__(512, 2)
__global__ void rnn_rec_kernel(const uint16_t* __restrict__ whhb,  // [H, H] bf16
                               const float* __restrict__ hx,       // [B, H] f32
                               float* __restrict__ out)            // [S*B*H | B*H] f32
{
    __shared__ __align__(16) uint16_t Asm[8 * 16 * 512];  // 128 KB: per-wave jt=3 A tiles
    __shared__ __align__(16) uint16_t hsm[512];           // h in bf16
    __shared__ __align__(16) float    ysm[512];           // y = Whh @ h

    const int tid  = threadIdx.x;   // 0..511
    const int lane = tid & 63;
    const int w    = tid >> 6;      // wave 0..7 -> rows [w*64, w*64+64)
    const int b    = blockIdx.x;    // batch
    const int r16  = lane & 15;
    const int q    = lane >> 4;     // 0..3

    // A fragments: rows j = w*64 + jt*16 + (lane&15), k = kt*32 + (lane>>4)*8 + e
    bf16x8 areg[48];
#pragma unroll
    for (int jt = 0; jt < 3; ++jt)
#pragma unroll
        for (int kt = 0; kt < 16; ++kt)
            areg[jt * 16 + kt] = *reinterpret_cast<const bf16x8*>(
                whhb + (size_t)(w * 64 + jt * 16 + r16) * H_SZ + kt * 32 + q * 8);
    // 4th j-subtile goes to LDS (re-read every step)
#pragma unroll
    for (int kt = 0; kt < 16; ++kt)
        *reinterpret_cast<bf16x8*>(&Asm[(w * 16 + kt) * 512 + lane * 8]) =
            *reinterpret_cast<const bf16x8*>(
                whhb + (size_t)(w * 64 + 48 + r16) * H_SZ + kt * 32 + q * 8);

    hsm[tid] = f2b(hx[(size_t)b * H_SZ + tid]);
    float xp_next = out[(size_t)b * H_SZ + tid];   // xp row for s=0
    __syncthreads();

    for (int s = 0; s < S_LEN; ++s) {
        f32x4 a0{0.f,0.f,0.f,0.f}, a1{0.f,0.f,0.f,0.f}, a2{0.f,0.f,0.f,0.f}, a3{0.f,0.f,0.f,0.f};
#pragma unroll
        for (int kt = 0; kt < 16; ++kt) {
            // B operand: all 16 cols get h[k] (broadcast read, conflict-free)
            bf16x8 bf = *reinterpret_cast<const bf16x8*>(&hsm[kt * 32 + q * 8]);
            bf16x8 al = *reinterpret_cast<const bf16x8*>(&Asm[(w * 16 + kt) * 512 + lane * 8]);
            a0 = __builtin_amdgcn_mfma_f32_16x16x32_bf16(areg[kt],      bf, a0, 0, 0, 0);
            a1 = __builtin_amdgcn_mfma_f32_16x16x32_bf16(areg[16 + kt], bf, a1, 0, 0, 0);
            a2 = __builtin_amdgcn_mfma_f32_16x16x32_bf16(areg[32 + kt], bf, a2, 0, 0, 0);
            a3 = __builtin_amdgcn_mfma_f32_16x16x32_bf16(al,            bf, a3, 0, 0, 0);
        }
        // C/D layout: col = lane&15 (use col 0), row = (lane>>4)*4 + r
        if (r16 == 0) {
#pragma unroll
            for (int r = 0; r < 4; ++r) {
                ysm[w * 64 +  0 + q * 4 + r] = a0[r];
                ysm[w * 64 + 16 + q * 4 + r] = a1[r];
                ysm[w * 64 + 32 + q * 4 + r] = a2[r];
                ysm[w * 64 + 48 + q * 4 + r] = a3[r];
            }
        }
        __syncthreads();

        float v  = ysm[tid] + xp_next;
        float e  = __expf(2.f * v);
        float th = 1.f - 2.f / (e + 1.f);
        out[((size_t)s * B_SZ + b) * H_SZ + tid] = th;             // overwrite xp row s
        if (s + 1 < S_LEN)
            xp_next = out[((size_t)(s + 1) * B_SZ + b) * H_SZ + tid];  // prefetch next xp
        hsm[tid] = f2b(th);
        if (s == S_LEN - 1)
            out[(size_t)S_LEN * B_SZ * H_SZ + (size_t)b * H_SZ + tid] = th;  // h_last
        __syncthreads();
    }
}

// ---------------- launcher ----------------
extern "C" void kernel_launch(void* const* d_in, const int* in_sizes, int n_in,
                              void* d_out, int out_size, void* d_ws, size_t ws_size,
                              hipStream_t stream) {
    const float* inp = (const float*)d_in[0];
    const float* hx  = (const float*)d_in[1];
    const float* wih = (const float*)d_in[2];
    const float* whh = (const float*)d_in[3];
    const float* bih = (const float*)d_in[4];
    const float* bhh = (const float*)d_in[5];
    float* out = (float*)d_out;

    uint16_t* wihb = (uint16_t*)d_ws;
    uint16_t* whhb = wihb + (size_t)H_SZ * I_SZ;

    cvt_weights_kernel<<<256, 256, 0, stream>>>(wih, whh, wihb, whhb);

    const int grid_gemm = (S_LEN * B_SZ / BM) * (H_SZ / BN);  // 4096
    xproj_gemm_kernel<<<grid_gemm, 256, 0, stream>>>(inp, wihb, bih, bhh, out);

    rnn_rec_kernel<<<B_SZ, 512, 0, stream>>>(whhb, hx, out);
}